// Round 5
// baseline (115.091 us; speedup 1.0000x reference)
//
#include <hip/hip_runtime.h>
#include <hip/hip_bf16.h>

// ---------------- types ----------------
typedef __bf16 bf16x8 __attribute__((ext_vector_type(8)));
typedef __bf16 bf16x4 __attribute__((ext_vector_type(4)));
typedef float  f32x4  __attribute__((ext_vector_type(4)));
typedef float  f32x4u __attribute__((ext_vector_type(4), aligned(4)));

// ---------------- problem constants ----------------
#define BATCH 128
#define NSOL  1027
#define IND   257
#define EMB   256
#define OUT_SRC  0ULL
#define OUT_CAND 32768ULL
#define OUT_DST  33587200ULL
#define OUT_DEP  33619968ULL

// workspace layout (bytes)
// W_eff bf16 MFMA-A-frag order, ALL 4 segs: [seg][kk(8)][cg(16)][lane(64)][j(8)]
#define WFRAG_OFF 0
#define WFRAG_SEG 131072
#define BEFF_OFF  524288     // b_eff fp32 [4][256]
#define W256_OFF  528384     // W_eff[:,k=256] fp32 [4][256]

// LDS tile buffer: 32 rows x 264 bf16 (528 B stride) + 32 f32 (k=256 col)
#define XST_B     528
#define X256_OFF_B 16896
#define BUF_B     17024

// ---------------- prep: build effective weights ----------------
__global__ __launch_bounds__(256) void swne_prep(
    const float* __restrict__ Wsrc, const float* __restrict__ bsrc,
    const float* __restrict__ Wdst, const float* __restrict__ bdst,
    const float* __restrict__ Wdep, const float* __restrict__ bdep,
    const float* __restrict__ Wcand, const float* __restrict__ bcand,
    const float* __restrict__ Wreg, const float* __restrict__ breg,
    const float* __restrict__ Wrand, const float* __restrict__ iw,
    char* __restrict__ ws)
{
    const float a  = 1.0f / (1.0f + expf(-iw[0]));
    const float ca = 1.0f - a;
    const float sa = 0.1f * a;

    const float* Ws[4] = {Wsrc, Wcand, Wdst, Wdep};
    const float* Bs[4] = {bsrc, bcand, bdst, bdep};

    const int gid = blockIdx.x * 256 + threadIdx.x;
    const int gsz = gridDim.x * 256;

    float* beff = (float*)(ws + BEFF_OFF);
    float* w256 = (float*)(ws + W256_OFF);
    for (int i = gid; i < 4 * EMB; i += gsz) {
        int seg = i >> 8, e = i & 255;
        beff[i] = ca * Bs[seg][e] + a * breg[e];
        int si = e * IND + 256;
        w256[i] = ca * Ws[seg][si] + a * Wreg[si] + sa * Wrand[si];
    }

    // W_eff bf16 MFMA-A-frag order for all 4 segs, k = 0..255
    __bf16* wfr = (__bf16*)(ws + WFRAG_OFF);
    for (int i = gid; i < 4 * 65536; i += gsz) {
        int seg  = i >> 16;
        int rem  = i & 65535;
        int kk   = rem >> 13;
        int rem2 = rem & 8191;
        int cg   = rem2 >> 9;
        int rem3 = rem2 & 511;
        int l    = rem3 >> 3;
        int j    = rem3 & 7;
        int e = cg * 16 + (l & 15);
        int k = kk * 32 + (l >> 4) * 8 + j;
        int si = e * IND + k;
        wfr[i] = (__bf16)(ca * Ws[seg][si] + a * Wreg[si] + sa * Wrand[si]);
    }
}

#define BARRIER() { asm volatile("s_waitcnt lgkmcnt(0)" ::: "memory"); \
  __builtin_amdgcn_s_barrier(); asm volatile("" ::: "memory"); }

// issue tile loads (per lane: 4 rows x f32x4; first 32 threads also k=256 col)
#define ISSUE(xb, pf, pf256) { \
  _Pragma("unroll") for (int rr = 0; rr < 4; ++rr) \
    pf[rr] = *((const f32x4u*)((xb) + (size_t)(wave * 4 + rr) * xstr) + lane); \
  if (tid < 32) pf256 = (xb)[(size_t)tid * xstr + 256]; }

// convert + write staged tile into LDS buffer b
#define WRITEB(b, pf, pf256) { \
  _Pragma("unroll") for (int rr = 0; rr < 4; ++rr) { \
    const int r_ = wave * 4 + rr; \
    bf16x4 h_; \
    h_[0] = (__bf16)pf[rr][0]; h_[1] = (__bf16)pf[rr][1]; \
    h_[2] = (__bf16)pf[rr][2]; h_[3] = (__bf16)pf[rr][3]; \
    *(bf16x4*)(smem + (b) * BUF_B + r_ * XST_B + lane * 8) = h_; } \
  if (tid < 32) *(float*)(smem + (b) * BUF_B + X256_OFF_B + tid * 4) = pf256; }

// ---------------- main: 12 edge tile-blocks + 1024 cand 4-tile blocks ----------------
__global__ __launch_bounds__(512, 4) void swne_main(const float* __restrict__ sol,
                                                    const char* __restrict__ ws,
                                                    float* __restrict__ out)
{
    __shared__ __align__(16) char smem[2 * BUF_B];   // 34 KiB double buffer
    const int tid = threadIdx.x, bid = blockIdx.x;
    const int lane = tid & 63, wave = tid >> 6;
    const int rl = lane & 15, grp = lane >> 4;

    const float* xbase; size_t xstr; float* obase; int seg, ntiles;
    size_t tstep_x, tstep_o;
    if (bid < 12) {
        const int s3 = bid >> 2;                     // 0:src 1:dst 2:dep
        seg = (s3 == 0) ? 0 : (s3 == 1 ? 2 : 3);
        const int nrow = (s3 == 0) ? 0 : (s3 == 1 ? 1025 : 1026);
        const size_t outb = (s3 == 0) ? OUT_SRC : (s3 == 1 ? OUT_DST : OUT_DEP);
        const int b0 = (bid & 3) * 32;
        xbase = sol + ((size_t)b0 * NSOL + nrow) * IND;
        xstr  = (size_t)NSOL * IND;
        obase = out + outb + (size_t)b0 * 256;
        ntiles = 1; tstep_x = 0; tstep_o = 0;
    } else {
        const int c = bid - 12;                      // 0..1023
        seg = 1;
        const int t0 = c * 4;
        const int bb = t0 >> 5, tr0 = t0 & 31;       // 4 tiles never cross a batch
        xbase = sol + ((size_t)bb * NSOL + 1 + tr0 * 32) * IND;
        xstr  = IND;
        obase = out + OUT_CAND + ((size_t)bb * 1024 + tr0 * 32) * 256;
        ntiles = 4;
        tstep_x = (size_t)32 * IND;
        tstep_o = (size_t)32 * 256;
    }

    // resident W fragments: this wave's 32 e-cols (64 VGPR)
    const bf16x8* wfs = (const bf16x8*)(ws + WFRAG_OFF) + (size_t)seg * 8192;
    bf16x8 wreg[8][2];
    #pragma unroll
    for (int kk = 0; kk < 8; ++kk)
        #pragma unroll
        for (int n = 0; n < 2; ++n)
            wreg[kk][n] = wfs[(size_t)((kk * 16 + wave * 2 + n) * 64 + lane)];

    const float* bc = (const float*)(ws + BEFF_OFF) + seg * 256;
    const float* wc = (const float*)(ws + W256_OFF) + seg * 256;

    f32x4 pfA[4]; float pfA256 = 0.f;

    // prologue: stage tile 0 into buffer 0
    ISSUE(xbase, pfA, pfA256);
    WRITEB(0, pfA, pfA256);
    BARRIER();

    for (int i = 0; i < ntiles; ++i) {
        const int cb = i & 1;
        const bool more = (i + 1 < ntiles);
        if (more) { const float* xn = xbase + (size_t)(i + 1) * tstep_x; ISSUE(xn, pfA, pfA256); }

        // ---- compute tile i from buf cb (W resident, LDS-only operands) ----
        f32x4 acc[2][2];
        #pragma unroll
        for (int rt = 0; rt < 2; ++rt)
            #pragma unroll
            for (int n = 0; n < 2; ++n) {
                f32x4 z = {0.f, 0.f, 0.f, 0.f};
                acc[rt][n] = z;
            }
        const char* xb = smem + cb * BUF_B;
        #pragma unroll
        for (int kk = 0; kk < 8; ++kk) {
            bf16x8 a0 = *(const bf16x8*)(xb + rl * XST_B + kk * 64 + grp * 16);
            bf16x8 a1 = *(const bf16x8*)(xb + (16 + rl) * XST_B + kk * 64 + grp * 16);
            #pragma unroll
            for (int n = 0; n < 2; ++n) {
                acc[0][n] = __builtin_amdgcn_mfma_f32_16x16x32_bf16(wreg[kk][n], a0, acc[0][n], 0, 0, 0);
                acc[1][n] = __builtin_amdgcn_mfma_f32_16x16x32_bf16(wreg[kk][n], a1, acc[1][n], 0, 0, 0);
            }
        }
        // ---- epilogue: bias + k=256 rank-1 term, f32x4 stores ----
        float* ob = obase + (size_t)i * tstep_o;
        #pragma unroll
        for (int rt = 0; rt < 2; ++rt) {
            const float xl = *(const float*)(xb + X256_OFF_B + (rt * 16 + rl) * 4);
            float* op = ob + (size_t)(rt * 16 + rl) * 256 + wave * 32 + grp * 4;
            #pragma unroll
            for (int n = 0; n < 2; ++n) {
                const int e0 = wave * 32 + n * 16 + grp * 4;
                f32x4 b4 = *(const f32x4*)(bc + e0);
                f32x4 w4 = *(const f32x4*)(wc + e0);
                f32x4 r = acc[rt][n] + xl * w4 + b4;
                *(f32x4*)(op + n * 16) = r;
            }
        }

        if (more) { WRITEB(cb ^ 1, pfA, pfA256); BARRIER(); }
    }
}

extern "C" void kernel_launch(void* const* d_in, const int* in_sizes, int n_in,
                              void* d_out, int out_size, void* d_ws, size_t ws_size,
                              hipStream_t stream) {
    const float* sol   = (const float*)d_in[0];
    const float* Wsrc  = (const float*)d_in[1];
    const float* bsrc  = (const float*)d_in[2];
    const float* Wdst  = (const float*)d_in[3];
    const float* bdst  = (const float*)d_in[4];
    const float* Wdep  = (const float*)d_in[5];
    const float* bdep  = (const float*)d_in[6];
    const float* Wcand = (const float*)d_in[7];
    const float* bcand = (const float*)d_in[8];
    const float* Wreg  = (const float*)d_in[9];
    const float* breg  = (const float*)d_in[10];
    const float* Wrand = (const float*)d_in[11];
    const float* iw    = (const float*)d_in[12];

    swne_prep<<<512, 256, 0, stream>>>(Wsrc, bsrc, Wdst, bdst, Wdep, bdep,
                                       Wcand, bcand, Wreg, breg, Wrand, iw,
                                       (char*)d_ws);
    swne_main<<<1036, 512, 0, stream>>>(sol, (const char*)d_ws, (float*)d_out);
}